// Round 2
// baseline (1138.853 us; speedup 1.0000x reference)
//
#include <hip/hip_runtime.h>

// ChebyshevKAN on MI355X (gfx950).
// Reformulation: einsum(bid,oid->bo) + x@base_w.T  ==  Xaug @ W^T with
//   Xaug[b, i*6+d] = T_{d+1}(tanh(x_i))  (d=0..4),  Xaug[b, i*6+5] = x_i
//   W[o,    i*6+d] = coeff[o,i,d+1]      (d=0..4),  W[o,    i*6+5] = base_w[o,i]
// T0==1 slice folds into bias:  bias'[o] = bias[o] + sum_i coeff[o,i,0].
// GEMMs run bf16 MFMA (16x16x32), fp32 accumulate; all nonlinearity in fp32.
//
// R2: (a) XOR chunk swizzle (applied on the global side of global_load_lds,
//     since the LDS side is forced to base+lane*16) kills the 128B-stride
//     bank conflicts (6.96e7 in R1). (b) GEMM1 uses BM=256 tile: grid=512
//     blocks = exactly 2/CU all-resident -> flat wavefront, less A re-fetch.

typedef __bf16 bf16x8 __attribute__((ext_vector_type(8)));
typedef float f32x4 __attribute__((ext_vector_type(4)));
typedef unsigned short u16x8 __attribute__((ext_vector_type(8)));

__device__ __forceinline__ unsigned short f2bf(float f) {
    unsigned int u = __float_as_uint(f);
    unsigned int r = (u + 0x7FFFu + ((u >> 16) & 1u)) >> 16;
    return (unsigned short)r;
}

__device__ __forceinline__ void cheb_pack(float s, unsigned short* o6) {
    float u  = tanhf(s);
    float T1 = u;
    float T2 = 2.f * u * u - 1.f;
    float T3 = 2.f * u * T2 - T1;
    float T4 = 2.f * u * T3 - T2;
    float T5 = 2.f * u * T4 - T3;
    o6[0] = f2bf(T1); o6[1] = f2bf(T2); o6[2] = f2bf(T3);
    o6[3] = f2bf(T4); o6[4] = f2bf(T5); o6[5] = f2bf(s);
}

__device__ __forceinline__ void load_lds16(const void* g, void* l) {
    __builtin_amdgcn_global_load_lds(
        (const __attribute__((address_space(1))) void*)g,
        (__attribute__((address_space(3))) void*)l, 16, 0, 0);
}

// ---------------- prep: weights [O,I,6]+[O,I] -> W[N=O, K=I*6] bf16 ----------
__global__ __launch_bounds__(256) void prep_w_kernel(
    const float* __restrict__ coeff, const float* __restrict__ base_w,
    unsigned short* __restrict__ W, int OI)
{
    int idx = blockIdx.x * 256 + threadIdx.x;
    if (idx >= OI) return;
    const float* c = coeff + (size_t)idx * 6;
    unsigned short w0 = f2bf(c[1]), w1 = f2bf(c[2]), w2 = f2bf(c[3]),
                   w3 = f2bf(c[4]), w4 = f2bf(c[5]), w5 = f2bf(base_w[idx]);
    unsigned int* d = (unsigned int*)(W + (size_t)idx * 6);
    d[0] = w0 | ((unsigned int)w1 << 16);
    d[1] = w2 | ((unsigned int)w3 << 16);
    d[2] = w4 | ((unsigned int)w5 << 16);
}

// bias'[o] = bias[o] + sum_i coeff[o,i,0]   (fp32, block per o)
__global__ __launch_bounds__(256) void prep_bias_kernel(
    const float* __restrict__ coeff, const float* __restrict__ bias,
    float* __restrict__ bp, int I)
{
    int o = blockIdx.x, tid = threadIdx.x;
    float s = 0.f;
    for (int i = tid; i < I; i += 256) s += coeff[((size_t)o * I + i) * 6];
    #pragma unroll
    for (int off = 32; off > 0; off >>= 1) s += __shfl_down(s, off);
    __shared__ float red[4];
    int lane = tid & 63, wv = tid >> 6;
    if (lane == 0) red[wv] = s;
    __syncthreads();
    if (tid == 0) bp[o] = bias[o] + red[0] + red[1] + red[2] + red[3];
}

// ---------------- expand1: x[b,1024] -> Xaug[b,6144] bf16  (block per row) ---
__global__ __launch_bounds__(256) void expand1_kernel(
    const float* __restrict__ x, unsigned short* __restrict__ Xa)
{
    int b = blockIdx.x, tid = threadIdx.x;
    f32x4 xv = *(const f32x4*)(x + (size_t)b * 1024 + tid * 4);
    alignas(16) unsigned short ov[24];
    #pragma unroll
    for (int e = 0; e < 4; e++) cheb_pack(tanhf(xv[e]), ov + e * 6);
    u16x8* dst = (u16x8*)(Xa + (size_t)b * 6144 + tid * 24);
    const u16x8* src = (const u16x8*)ov;
    dst[0] = src[0]; dst[1] = src[1]; dst[2] = src[2];
}

// ------------- LN + SiLU + expand2 fused (block per row of 1024) -------------
__global__ __launch_bounds__(256) void ln_silu_expand_kernel(
    const float* __restrict__ H, const float* __restrict__ gamma,
    const float* __restrict__ beta, unsigned short* __restrict__ Xa)
{
    int b = blockIdx.x, tid = threadIdx.x;
    f32x4 hv = *(const f32x4*)(H + (size_t)b * 1024 + tid * 4);
    float s1 = hv[0] + hv[1] + hv[2] + hv[3];
    float s2 = hv[0]*hv[0] + hv[1]*hv[1] + hv[2]*hv[2] + hv[3]*hv[3];
    #pragma unroll
    for (int off = 32; off > 0; off >>= 1) {
        s1 += __shfl_down(s1, off);
        s2 += __shfl_down(s2, off);
    }
    __shared__ float red[8];
    __shared__ float stats[2];
    int lane = tid & 63, wv = tid >> 6;
    if (lane == 0) { red[wv] = s1; red[4 + wv] = s2; }
    __syncthreads();
    if (tid == 0) {
        float t1 = red[0] + red[1] + red[2] + red[3];
        float t2 = red[4] + red[5] + red[6] + red[7];
        float mu = t1 * (1.f / 1024.f);
        float var = t2 * (1.f / 1024.f) - mu * mu;
        stats[0] = mu;
        stats[1] = rsqrtf(var + 1e-5f);
    }
    __syncthreads();
    float mu = stats[0], rs = stats[1];
    f32x4 g  = *(const f32x4*)(gamma + tid * 4);
    f32x4 bt = *(const f32x4*)(beta  + tid * 4);
    alignas(16) unsigned short ov[24];
    #pragma unroll
    for (int e = 0; e < 4; e++) {
        float y = (hv[e] - mu) * rs * g[e] + bt[e];
        float s = y / (1.f + expf(-y));   // SiLU
        cheb_pack(s, ov + e * 6);
    }
    u16x8* dst = (u16x8*)(Xa + (size_t)b * 6144 + tid * 24);
    const u16x8* src = (const u16x8*)ov;
    dst[0] = src[0]; dst[1] = src[1]; dst[2] = src[2];
}

// ---------------- bf16 GEMM: C[M,N] = A[M,K] * W[N,K]^T + bias ---------------
// BM x 128 tile, BK=64, global_load_lds width-16 staging with XOR chunk
// swizzle; 4 waves, each owning a (BM/2) x 64 quadrant as (BM/32) x 4 of
// 16x16x32 MFMAs.
//
// LDS layout: 16B slot q holds row r=q/8, chunk c where (c ^ (r&7)) == q%8.
// Staging (forced lds = base+lane*16) fetches global chunk
// c = (tid&7)^((tid>>3)&7); frag reads address row*64 + ((ci^(fr&7))*8):
// 64 lanes spread 2-per-bank-group -> conflict-free (2-way is free, m136).
template<int BM>
__global__ __launch_bounds__(256) void gemm_kernel(
    const unsigned short* __restrict__ A,   // [M,K] bf16 bits
    const unsigned short* __restrict__ Wt,  // [N,K] bf16 bits
    const float* __restrict__ bias,         // [N]
    float* __restrict__ C,                  // [M,N] fp32
    int N, int K)
{
    constexpr int MI = BM / 32;             // A-frags per wave
    __shared__ __align__(16) unsigned short As[BM * 64];
    __shared__ __align__(16) unsigned short Bs[128 * 64];
    const int tid  = threadIdx.x;
    const int lane = tid & 63;
    const int wave = tid >> 6;
    const int ntn  = N >> 7;
    const size_t m0 = (size_t)(blockIdx.x / ntn) * BM;
    const size_t n0 = (size_t)(blockIdx.x % ntn) << 7;
    const int wr = (wave >> 1) * (BM / 2);  // wave's quadrant rows
    const int wc = (wave & 1) * 64;         // wave's quadrant cols
    const int fr = lane & 15;               // MFMA operand row
    const int cg = lane >> 4;               // chunk-group 0..3 (fk = cg*8)
    const int srow = tid >> 3;              // staging row within 32-row stripe
    const int schunk = (tid & 7) ^ (srow & 7);  // swizzled global chunk

    f32x4 acc[MI][4];
    #pragma unroll
    for (int i = 0; i < MI; i++)
        #pragma unroll
        for (int j = 0; j < 4; j++) acc[i][j] = f32x4{0.f, 0.f, 0.f, 0.f};

    for (int k0 = 0; k0 < K; k0 += 64) {
        #pragma unroll
        for (int s = 0; s < BM / 32; ++s) {
            const unsigned short* ga =
                A + (m0 + s * 32 + srow) * K + (k0 + schunk * 8);
            load_lds16(ga, &As[(s * 256 + wave * 64) * 8]);
        }
        #pragma unroll
        for (int s = 0; s < 4; ++s) {
            const unsigned short* gb =
                Wt + (n0 + s * 32 + srow) * K + (k0 + schunk * 8);
            load_lds16(gb, &Bs[(s * 256 + wave * 64) * 8]);
        }
        __syncthreads();
        #pragma unroll
        for (int kk = 0; kk < 64; kk += 32) {
            bf16x8 af[MI], bfr[4];
            #pragma unroll
            for (int i = 0; i < MI; i++) {
                const int rr = wr + i * 16 + fr;
                const int swz = ((kk / 8 + cg) ^ (fr & 7)) * 8;
                af[i] = *(const bf16x8*)&As[rr * 64 + swz];
            }
            #pragma unroll
            for (int j = 0; j < 4; j++) {
                const int rr = wc + j * 16 + fr;
                const int swz = ((kk / 8 + cg) ^ (fr & 7)) * 8;
                bfr[j] = *(const bf16x8*)&Bs[rr * 64 + swz];
            }
            #pragma unroll
            for (int i = 0; i < MI; i++)
                #pragma unroll
                for (int j = 0; j < 4; j++)
                    acc[i][j] = __builtin_amdgcn_mfma_f32_16x16x32_bf16(
                        af[i], bfr[j], acc[i][j], 0, 0, 0);
        }
        __syncthreads();
    }

    // C/D layout (verified m89/m91): col = lane&15, row = (lane>>4)*4 + reg
    const int rbase = wr + (lane >> 4) * 4;
    const int cbase = wc + (lane & 15);
    #pragma unroll
    for (int j = 0; j < 4; j++) {
        const int col = (int)n0 + cbase + j * 16;
        const float bv = bias[col];
        #pragma unroll
        for (int i = 0; i < MI; i++) {
            float* cp = C + (m0 + rbase + i * 16) * N + col;
            #pragma unroll
            for (int r = 0; r < 4; r++) cp[(size_t)r * N] = acc[i][j][r] + bv;
        }
    }
}

extern "C" void kernel_launch(void* const* d_in, const int* in_sizes, int n_in,
                              void* d_out, int out_size, void* d_ws, size_t ws_size,
                              hipStream_t stream)
{
    const float* x       = (const float*)d_in[0];
    const float* coeff1  = (const float*)d_in[1];
    const float* base_w1 = (const float*)d_in[2];
    const float* bias1   = (const float*)d_in[3];
    const float* gamma   = (const float*)d_in[4];
    const float* beta    = (const float*)d_in[5];
    const float* coeff2  = (const float*)d_in[6];
    const float* base_w2 = (const float*)d_in[7];
    const float* bias2   = (const float*)d_in[8];
    float* out = (float*)d_out;

    const int B = 16384, D0 = 1024, D1 = 1024, D2 = 512;
    const int K1 = D0 * 6, K2 = D1 * 6;   // 6144 each

    // workspace layout
    char* base = (char*)d_ws;
    size_t off = 0;
    unsigned short* W1 = (unsigned short*)(base + off); off += (size_t)D1 * K1 * 2;
    unsigned short* W2 = (unsigned short*)(base + off); off += (size_t)D2 * K2 * 2;
    float* b1p = (float*)(base + off); off += (size_t)D1 * 4;
    float* b2p = (float*)(base + off); off += (size_t)D2 * 4;
    off = (off + 255) & ~(size_t)255;

    // chunk rows so Xaug (K1 bf16) + h (D1 f32) fit in remaining ws; keep %256
    size_t per_row = (size_t)K1 * 2 + (size_t)D1 * 4;   // 16384 B
    long long avail = (long long)ws_size - (long long)off;
    long long mcl = avail > 0 ? avail / (long long)per_row : 0;
    int Mc = (int)((mcl / 256) * 256);
    if (Mc < 256) Mc = 256;
    if (Mc > B) Mc = B;

    unsigned short* Xa = (unsigned short*)(base + off);
    float* h = (float*)(base + off + (size_t)Mc * K1 * 2);

    prep_w_kernel<<<(D1 * D0 + 255) / 256, 256, 0, stream>>>(coeff1, base_w1, W1, D1 * D0);
    prep_w_kernel<<<(D2 * D1 + 255) / 256, 256, 0, stream>>>(coeff2, base_w2, W2, D2 * D1);
    prep_bias_kernel<<<D1, 256, 0, stream>>>(coeff1, bias1, b1p, D0);
    prep_bias_kernel<<<D2, 256, 0, stream>>>(coeff2, bias2, b2p, D1);

    for (int m0 = 0; m0 < B; m0 += Mc) {
        int rows = (B - m0 < Mc) ? (B - m0) : Mc;
        expand1_kernel<<<rows, 256, 0, stream>>>(x + (size_t)m0 * D0, Xa);
        gemm_kernel<256><<<(rows / 256) * (D1 / 128), 256, 0, stream>>>(
            Xa, W1, b1p, h, D1, K1);
        ln_silu_expand_kernel<<<rows, 256, 0, stream>>>(h, gamma, beta, Xa);
        gemm_kernel<128><<<(rows / 128) * (D2 / 128), 256, 0, stream>>>(
            Xa, W2, b2p, out + (size_t)m0 * D2, D2, K2);
    }
}

// Round 3
// 967.513 us; speedup vs baseline: 1.1771x; 1.1771x over previous
//
#include <hip/hip_runtime.h>

// ChebyshevKAN on MI355X (gfx950).
// Reformulation: einsum(bid,oid->bo) + x@base_w.T  ==  Xaug @ W^T with
//   Xaug[b, i*6+d] = T_{d+1}(tanh(x_i))  (d=0..4),  Xaug[b, i*6+5] = x_i
//   W[o,    i*6+d] = coeff[o,i,d+1]      (d=0..4),  W[o,    i*6+5] = base_w[o,i]
// T0==1 slice folds into bias:  bias'[o] = bias[o] + sum_i coeff[o,i,0].
// GEMMs run bf16 MFMA (16x16x32), fp32 accumulate; all nonlinearity in fp32.
//
// R3: BM=128 (R1's occupancy: 88 VGPR, 32KB LDS, ~4 blocks/CU) + R2's XOR
// chunk swizzle (verified: SQ_LDS_BANK_CONFLICT 6.96e7 -> 0). R2's BM=256
// halved occupancy (168 VGPR / 48KB LDS) and regressed — reverted.

typedef __bf16 bf16x8 __attribute__((ext_vector_type(8)));
typedef float f32x4 __attribute__((ext_vector_type(4)));
typedef unsigned short u16x8 __attribute__((ext_vector_type(8)));

__device__ __forceinline__ unsigned short f2bf(float f) {
    unsigned int u = __float_as_uint(f);
    unsigned int r = (u + 0x7FFFu + ((u >> 16) & 1u)) >> 16;
    return (unsigned short)r;
}

__device__ __forceinline__ void cheb_pack(float s, unsigned short* o6) {
    float u  = tanhf(s);
    float T1 = u;
    float T2 = 2.f * u * u - 1.f;
    float T3 = 2.f * u * T2 - T1;
    float T4 = 2.f * u * T3 - T2;
    float T5 = 2.f * u * T4 - T3;
    o6[0] = f2bf(T1); o6[1] = f2bf(T2); o6[2] = f2bf(T3);
    o6[3] = f2bf(T4); o6[4] = f2bf(T5); o6[5] = f2bf(s);
}

__device__ __forceinline__ void load_lds16(const void* g, void* l) {
    __builtin_amdgcn_global_load_lds(
        (const __attribute__((address_space(1))) void*)g,
        (__attribute__((address_space(3))) void*)l, 16, 0, 0);
}

// ---------------- prep: weights [O,I,6]+[O,I] -> W[N=O, K=I*6] bf16 ----------
__global__ __launch_bounds__(256) void prep_w_kernel(
    const float* __restrict__ coeff, const float* __restrict__ base_w,
    unsigned short* __restrict__ W, int OI)
{
    int idx = blockIdx.x * 256 + threadIdx.x;
    if (idx >= OI) return;
    const float* c = coeff + (size_t)idx * 6;
    unsigned short w0 = f2bf(c[1]), w1 = f2bf(c[2]), w2 = f2bf(c[3]),
                   w3 = f2bf(c[4]), w4 = f2bf(c[5]), w5 = f2bf(base_w[idx]);
    unsigned int* d = (unsigned int*)(W + (size_t)idx * 6);
    d[0] = w0 | ((unsigned int)w1 << 16);
    d[1] = w2 | ((unsigned int)w3 << 16);
    d[2] = w4 | ((unsigned int)w5 << 16);
}

// bias'[o] = bias[o] + sum_i coeff[o,i,0]   (fp32, block per o)
__global__ __launch_bounds__(256) void prep_bias_kernel(
    const float* __restrict__ coeff, const float* __restrict__ bias,
    float* __restrict__ bp, int I)
{
    int o = blockIdx.x, tid = threadIdx.x;
    float s = 0.f;
    for (int i = tid; i < I; i += 256) s += coeff[((size_t)o * I + i) * 6];
    #pragma unroll
    for (int off = 32; off > 0; off >>= 1) s += __shfl_down(s, off);
    __shared__ float red[4];
    int lane = tid & 63, wv = tid >> 6;
    if (lane == 0) red[wv] = s;
    __syncthreads();
    if (tid == 0) bp[o] = bias[o] + red[0] + red[1] + red[2] + red[3];
}

// ---------------- expand1: x[b,1024] -> Xaug[b,6144] bf16  (block per row) ---
__global__ __launch_bounds__(256) void expand1_kernel(
    const float* __restrict__ x, unsigned short* __restrict__ Xa)
{
    int b = blockIdx.x, tid = threadIdx.x;
    f32x4 xv = *(const f32x4*)(x + (size_t)b * 1024 + tid * 4);
    alignas(16) unsigned short ov[24];
    #pragma unroll
    for (int e = 0; e < 4; e++) cheb_pack(tanhf(xv[e]), ov + e * 6);
    u16x8* dst = (u16x8*)(Xa + (size_t)b * 6144 + tid * 24);
    const u16x8* src = (const u16x8*)ov;
    dst[0] = src[0]; dst[1] = src[1]; dst[2] = src[2];
}

// ------------- LN + SiLU + expand2 fused (block per row of 1024) -------------
__global__ __launch_bounds__(256) void ln_silu_expand_kernel(
    const float* __restrict__ H, const float* __restrict__ gamma,
    const float* __restrict__ beta, unsigned short* __restrict__ Xa)
{
    int b = blockIdx.x, tid = threadIdx.x;
    f32x4 hv = *(const f32x4*)(H + (size_t)b * 1024 + tid * 4);
    float s1 = hv[0] + hv[1] + hv[2] + hv[3];
    float s2 = hv[0]*hv[0] + hv[1]*hv[1] + hv[2]*hv[2] + hv[3]*hv[3];
    #pragma unroll
    for (int off = 32; off > 0; off >>= 1) {
        s1 += __shfl_down(s1, off);
        s2 += __shfl_down(s2, off);
    }
    __shared__ float red[8];
    __shared__ float stats[2];
    int lane = tid & 63, wv = tid >> 6;
    if (lane == 0) { red[wv] = s1; red[4 + wv] = s2; }
    __syncthreads();
    if (tid == 0) {
        float t1 = red[0] + red[1] + red[2] + red[3];
        float t2 = red[4] + red[5] + red[6] + red[7];
        float mu = t1 * (1.f / 1024.f);
        float var = t2 * (1.f / 1024.f) - mu * mu;
        stats[0] = mu;
        stats[1] = rsqrtf(var + 1e-5f);
    }
    __syncthreads();
    float mu = stats[0], rs = stats[1];
    f32x4 g  = *(const f32x4*)(gamma + tid * 4);
    f32x4 bt = *(const f32x4*)(beta  + tid * 4);
    alignas(16) unsigned short ov[24];
    #pragma unroll
    for (int e = 0; e < 4; e++) {
        float y = (hv[e] - mu) * rs * g[e] + bt[e];
        float s = y / (1.f + expf(-y));   // SiLU
        cheb_pack(s, ov + e * 6);
    }
    u16x8* dst = (u16x8*)(Xa + (size_t)b * 6144 + tid * 24);
    const u16x8* src = (const u16x8*)ov;
    dst[0] = src[0]; dst[1] = src[1]; dst[2] = src[2];
}

// ---------------- bf16 GEMM: C[M,N] = A[M,K] * W[N,K]^T + bias ---------------
// 128 x 128 tile, BK=64, global_load_lds width-16 staging with XOR chunk
// swizzle; 4 waves, each owning a 64 x 64 quadrant as 4 x 4 of
// 16x16x32 MFMAs.
//
// LDS layout: 16B slot q holds row r=q/8, chunk c where (c ^ (r&7)) == q%8.
// Staging (forced lds = base+lane*16) fetches global chunk
// c = (tid&7)^((tid>>3)&7); frag reads address row*64 + ((ci^(fr&7))*8):
// 64 lanes spread 2-per-bank -> conflict-free (2-way is free, m136).
// Verified R2: SQ_LDS_BANK_CONFLICT = 0, absmax unchanged.
__global__ __launch_bounds__(256) void gemm_kernel(
    const unsigned short* __restrict__ A,   // [M,K] bf16 bits
    const unsigned short* __restrict__ Wt,  // [N,K] bf16 bits
    const float* __restrict__ bias,         // [N]
    float* __restrict__ C,                  // [M,N] fp32
    int N, int K)
{
    __shared__ __align__(16) unsigned short As[128 * 64];
    __shared__ __align__(16) unsigned short Bs[128 * 64];
    const int tid  = threadIdx.x;
    const int lane = tid & 63;
    const int wave = tid >> 6;
    const int ntn  = N >> 7;
    const size_t m0 = (size_t)(blockIdx.x / ntn) << 7;
    const size_t n0 = (size_t)(blockIdx.x % ntn) << 7;
    const int wr = (wave >> 1) * 64;        // wave's quadrant rows
    const int wc = (wave & 1) * 64;         // wave's quadrant cols
    const int fr = lane & 15;               // MFMA operand row
    const int cg = lane >> 4;               // chunk-group 0..3 (fk = cg*8)
    const int srow = tid >> 3;              // staging row within 32-row stripe
    const int schunk = (tid & 7) ^ (srow & 7);  // swizzled global chunk

    f32x4 acc[4][4];
    #pragma unroll
    for (int i = 0; i < 4; i++)
        #pragma unroll
        for (int j = 0; j < 4; j++) acc[i][j] = f32x4{0.f, 0.f, 0.f, 0.f};

    for (int k0 = 0; k0 < K; k0 += 64) {
        #pragma unroll
        for (int s = 0; s < 4; ++s) {
            const unsigned short* ga =
                A + (m0 + s * 32 + srow) * K + (k0 + schunk * 8);
            load_lds16(ga, &As[(s * 256 + wave * 64) * 8]);
        }
        #pragma unroll
        for (int s = 0; s < 4; ++s) {
            const unsigned short* gb =
                Wt + (n0 + s * 32 + srow) * K + (k0 + schunk * 8);
            load_lds16(gb, &Bs[(s * 256 + wave * 64) * 8]);
        }
        __syncthreads();
        #pragma unroll
        for (int kk = 0; kk < 64; kk += 32) {
            bf16x8 af[4], bfr[4];
            #pragma unroll
            for (int i = 0; i < 4; i++) {
                const int rr = wr + i * 16 + fr;
                const int swz = ((kk / 8 + cg) ^ (fr & 7)) * 8;
                af[i] = *(const bf16x8*)&As[rr * 64 + swz];
            }
            #pragma unroll
            for (int j = 0; j < 4; j++) {
                const int rr = wc + j * 16 + fr;
                const int swz = ((kk / 8 + cg) ^ (fr & 7)) * 8;
                bfr[j] = *(const bf16x8*)&Bs[rr * 64 + swz];
            }
            #pragma unroll
            for (int i = 0; i < 4; i++)
                #pragma unroll
                for (int j = 0; j < 4; j++)
                    acc[i][j] = __builtin_amdgcn_mfma_f32_16x16x32_bf16(
                        af[i], bfr[j], acc[i][j], 0, 0, 0);
        }
        __syncthreads();
    }

    // C/D layout (verified m89/m91): col = lane&15, row = (lane>>4)*4 + reg
    const int rbase = wr + (lane >> 4) * 4;
    const int cbase = wc + (lane & 15);
    #pragma unroll
    for (int j = 0; j < 4; j++) {
        const int col = (int)n0 + cbase + j * 16;
        const float bv = bias[col];
        #pragma unroll
        for (int i = 0; i < 4; i++) {
            float* cp = C + (m0 + rbase + i * 16) * N + col;
            #pragma unroll
            for (int r = 0; r < 4; r++) cp[(size_t)r * N] = acc[i][j][r] + bv;
        }
    }
}

extern "C" void kernel_launch(void* const* d_in, const int* in_sizes, int n_in,
                              void* d_out, int out_size, void* d_ws, size_t ws_size,
                              hipStream_t stream)
{
    const float* x       = (const float*)d_in[0];
    const float* coeff1  = (const float*)d_in[1];
    const float* base_w1 = (const float*)d_in[2];
    const float* bias1   = (const float*)d_in[3];
    const float* gamma   = (const float*)d_in[4];
    const float* beta    = (const float*)d_in[5];
    const float* coeff2  = (const float*)d_in[6];
    const float* base_w2 = (const float*)d_in[7];
    const float* bias2   = (const float*)d_in[8];
    float* out = (float*)d_out;

    const int B = 16384, D0 = 1024, D1 = 1024, D2 = 512;
    const int K1 = D0 * 6, K2 = D1 * 6;   // 6144 each

    // workspace layout
    char* base = (char*)d_ws;
    size_t off = 0;
    unsigned short* W1 = (unsigned short*)(base + off); off += (size_t)D1 * K1 * 2;
    unsigned short* W2 = (unsigned short*)(base + off); off += (size_t)D2 * K2 * 2;
    float* b1p = (float*)(base + off); off += (size_t)D1 * 4;
    float* b2p = (float*)(base + off); off += (size_t)D2 * 4;
    off = (off + 255) & ~(size_t)255;

    // chunk rows so Xaug (K1 bf16) + h (D1 f32) fit in remaining ws; keep %128
    size_t per_row = (size_t)K1 * 2 + (size_t)D1 * 4;   // 16384 B
    long long avail = (long long)ws_size - (long long)off;
    long long mcl = avail > 0 ? avail / (long long)per_row : 0;
    int Mc = (int)((mcl / 128) * 128);
    if (Mc < 128) Mc = 128;
    if (Mc > B) Mc = B;

    unsigned short* Xa = (unsigned short*)(base + off);
    float* h = (float*)(base + off + (size_t)Mc * K1 * 2);

    prep_w_kernel<<<(D1 * D0 + 255) / 256, 256, 0, stream>>>(coeff1, base_w1, W1, D1 * D0);
    prep_w_kernel<<<(D2 * D1 + 255) / 256, 256, 0, stream>>>(coeff2, base_w2, W2, D2 * D1);
    prep_bias_kernel<<<D1, 256, 0, stream>>>(coeff1, bias1, b1p, D0);
    prep_bias_kernel<<<D2, 256, 0, stream>>>(coeff2, bias2, b2p, D1);

    for (int m0 = 0; m0 < B; m0 += Mc) {
        int rows = (B - m0 < Mc) ? (B - m0) : Mc;
        expand1_kernel<<<rows, 256, 0, stream>>>(x + (size_t)m0 * D0, Xa);
        gemm_kernel<<<(rows / 128) * (D1 / 128), 256, 0, stream>>>(
            Xa, W1, b1p, h, D1, K1);
        ln_silu_expand_kernel<<<rows, 256, 0, stream>>>(h, gamma, beta, Xa);
        gemm_kernel<<<(rows / 128) * (D2 / 128), 256, 0, stream>>>(
            Xa, W2, b2p, out + (size_t)m0 * D2, D2, K2);
    }
}

// Round 4
// 948.951 us; speedup vs baseline: 1.2001x; 1.0196x over previous
//
#include <hip/hip_runtime.h>

// ChebyshevKAN on MI355X (gfx950).
// Reformulation: einsum(bid,oid->bo) + x@base_w.T  ==  Xaug @ W^T with
//   Xaug[b, i*6+d] = T_{d+1}(tanh(x_i))  (d=0..4),  Xaug[b, i*6+5] = x_i
//   W[o,    i*6+d] = coeff[o,i,d+1]      (d=0..4),  W[o,    i*6+5] = base_w[o,i]
// T0==1 slice folds into bias:  bias'[o] = bias[o] + sum_i coeff[o,i,0].
// GEMMs run bf16 MFMA (16x16x32), fp32 accumulate; nonlinearity in fp32.
//
// R4: (1) frag LDS addresses hoisted out of K-loop (R3 recomputed the XOR
// swizzle per kk -> VALUBusy 32%); (2) XCD-affinity block swizzle: XCD owns
// an m-range so each A-panel is fetched by exactly one XCD (R3 FETCH 737MB
// vs 214 ideal); (3) fast tanh/sigmoid via v_exp_f32+v_rcp_f32 (libm tanhf
// was ~100 VALU ops x 33M calls in the expand kernels).

typedef __bf16 bf16x8 __attribute__((ext_vector_type(8)));
typedef float f32x4 __attribute__((ext_vector_type(4)));
typedef unsigned short u16x8 __attribute__((ext_vector_type(8)));

__device__ __forceinline__ unsigned short f2bf(float f) {
    unsigned int u = __float_as_uint(f);
    unsigned int r = (u + 0x7FFFu + ((u >> 16) & 1u)) >> 16;
    return (unsigned short)r;
}

// tanh via hardware exp/rcp: err ~1e-6, way below bf16 quantization.
__device__ __forceinline__ float fast_tanh(float x) {
    float a = fminf(fmaxf(x, -15.f), 15.f);
    float e = __expf(2.f * a);                       // v_exp_f32 path
    return 1.f - 2.f * __builtin_amdgcn_rcpf(e + 1.f); // v_rcp_f32
}

__device__ __forceinline__ float fast_silu(float y) {
    float a = fminf(fmaxf(y, -30.f), 30.f);
    return y * __builtin_amdgcn_rcpf(1.f + __expf(-a));
}

// s -> [T1(u),T2(u),T3(u),T4(u),T5(u), s] with u = tanh(s), as bf16 bits
__device__ __forceinline__ void cheb_pack(float s, unsigned short* o6) {
    float u  = fast_tanh(s);
    float T1 = u;
    float T2 = 2.f * u * u - 1.f;
    float T3 = 2.f * u * T2 - T1;
    float T4 = 2.f * u * T3 - T2;
    float T5 = 2.f * u * T4 - T3;
    o6[0] = f2bf(T1); o6[1] = f2bf(T2); o6[2] = f2bf(T3);
    o6[3] = f2bf(T4); o6[4] = f2bf(T5); o6[5] = f2bf(s);
}

__device__ __forceinline__ void load_lds16(const void* g, void* l) {
    __builtin_amdgcn_global_load_lds(
        (const __attribute__((address_space(1))) void*)g,
        (__attribute__((address_space(3))) void*)l, 16, 0, 0);
}

// ---------------- prep: weights [O,I,6]+[O,I] -> W[N=O, K=I*6] bf16 ----------
__global__ __launch_bounds__(256) void prep_w_kernel(
    const float* __restrict__ coeff, const float* __restrict__ base_w,
    unsigned short* __restrict__ W, int OI)
{
    int idx = blockIdx.x * 256 + threadIdx.x;
    if (idx >= OI) return;
    const float* c = coeff + (size_t)idx * 6;
    unsigned short w0 = f2bf(c[1]), w1 = f2bf(c[2]), w2 = f2bf(c[3]),
                   w3 = f2bf(c[4]), w4 = f2bf(c[5]), w5 = f2bf(base_w[idx]);
    unsigned int* d = (unsigned int*)(W + (size_t)idx * 6);
    d[0] = w0 | ((unsigned int)w1 << 16);
    d[1] = w2 | ((unsigned int)w3 << 16);
    d[2] = w4 | ((unsigned int)w5 << 16);
}

// bias'[o] = bias[o] + sum_i coeff[o,i,0]   (fp32, block per o)
__global__ __launch_bounds__(256) void prep_bias_kernel(
    const float* __restrict__ coeff, const float* __restrict__ bias,
    float* __restrict__ bp, int I)
{
    int o = blockIdx.x, tid = threadIdx.x;
    float s = 0.f;
    for (int i = tid; i < I; i += 256) s += coeff[((size_t)o * I + i) * 6];
    #pragma unroll
    for (int off = 32; off > 0; off >>= 1) s += __shfl_down(s, off);
    __shared__ float red[4];
    int lane = tid & 63, wv = tid >> 6;
    if (lane == 0) red[wv] = s;
    __syncthreads();
    if (tid == 0) bp[o] = bias[o] + red[0] + red[1] + red[2] + red[3];
}

// ---------------- expand1: x[b,1024] -> Xaug[b,6144] bf16  (block per row) ---
__global__ __launch_bounds__(256) void expand1_kernel(
    const float* __restrict__ x, unsigned short* __restrict__ Xa)
{
    int b = blockIdx.x, tid = threadIdx.x;
    f32x4 xv = *(const f32x4*)(x + (size_t)b * 1024 + tid * 4);
    alignas(16) unsigned short ov[24];
    #pragma unroll
    for (int e = 0; e < 4; e++) cheb_pack(fast_tanh(xv[e]), ov + e * 6);
    u16x8* dst = (u16x8*)(Xa + (size_t)b * 6144 + tid * 24);
    const u16x8* src = (const u16x8*)ov;
    dst[0] = src[0]; dst[1] = src[1]; dst[2] = src[2];
}

// ------------- LN + SiLU + expand2 fused (block per row of 1024) -------------
__global__ __launch_bounds__(256) void ln_silu_expand_kernel(
    const float* __restrict__ H, const float* __restrict__ gamma,
    const float* __restrict__ beta, unsigned short* __restrict__ Xa)
{
    int b = blockIdx.x, tid = threadIdx.x;
    f32x4 hv = *(const f32x4*)(H + (size_t)b * 1024 + tid * 4);
    float s1 = hv[0] + hv[1] + hv[2] + hv[3];
    float s2 = hv[0]*hv[0] + hv[1]*hv[1] + hv[2]*hv[2] + hv[3]*hv[3];
    #pragma unroll
    for (int off = 32; off > 0; off >>= 1) {
        s1 += __shfl_down(s1, off);
        s2 += __shfl_down(s2, off);
    }
    __shared__ float red[8];
    __shared__ float stats[2];
    int lane = tid & 63, wv = tid >> 6;
    if (lane == 0) { red[wv] = s1; red[4 + wv] = s2; }
    __syncthreads();
    if (tid == 0) {
        float t1 = red[0] + red[1] + red[2] + red[3];
        float t2 = red[4] + red[5] + red[6] + red[7];
        float mu = t1 * (1.f / 1024.f);
        float var = t2 * (1.f / 1024.f) - mu * mu;
        stats[0] = mu;
        stats[1] = rsqrtf(var + 1e-5f);
    }
    __syncthreads();
    float mu = stats[0], rs = stats[1];
    f32x4 g  = *(const f32x4*)(gamma + tid * 4);
    f32x4 bt = *(const f32x4*)(beta  + tid * 4);
    alignas(16) unsigned short ov[24];
    #pragma unroll
    for (int e = 0; e < 4; e++) {
        float y = (hv[e] - mu) * rs * g[e] + bt[e];
        cheb_pack(fast_silu(y), ov + e * 6);
    }
    u16x8* dst = (u16x8*)(Xa + (size_t)b * 6144 + tid * 24);
    const u16x8* src = (const u16x8*)ov;
    dst[0] = src[0]; dst[1] = src[1]; dst[2] = src[2];
}

// ---------------- bf16 GEMM: C[M,N] = A[M,K] * W[N,K]^T + bias ---------------
// 128x128 tile, BK=64, global_load_lds width-16 staging with XOR chunk
// swizzle (SQ_LDS_BANK_CONFLICT==0, verified R2/R3); 4 waves, each a 64x64
// quadrant of 4x4 16x16x32 MFMAs. Frag LDS base pointers hoisted out of the
// K-loop (kk & i/j become ds_read immediates). XCD-affinity block swizzle:
// xcd=b&7 owns a contiguous m-tile range so each A-panel is fetched by one
// XCD only; B panel cycles innermost (LLC-resident).
__global__ __launch_bounds__(256) void gemm_kernel(
    const unsigned short* __restrict__ A,   // [M,K] bf16 bits
    const unsigned short* __restrict__ Wt,  // [N,K] bf16 bits
    const float* __restrict__ bias,         // [N]
    float* __restrict__ C,                  // [M,N] fp32
    int N, int K)
{
    __shared__ __align__(16) unsigned short As[128 * 64];
    __shared__ __align__(16) unsigned short Bs[128 * 64];
    const int tid  = threadIdx.x;
    const int lane = tid & 63;
    const int wave = tid >> 6;
    const int ntn  = N >> 7;

    // XCD-affinity swizzle (perf heuristic only; bijective either way)
    int bkid = blockIdx.x;
    const int nm = gridDim.x / ntn;
    int mt, nt;
    if ((nm & 7) == 0) {
        const int mg = nm >> 3;
        const int s  = bkid >> 3;
        const int q  = s / ntn;
        mt = (bkid & 7) * mg + q;
        nt = s - q * ntn;
    } else {
        mt = bkid / ntn; nt = bkid % ntn;
    }
    const size_t m0 = (size_t)mt << 7;
    const size_t n0 = (size_t)nt << 7;

    const int wr = (wave >> 1) * 64;        // wave's quadrant rows
    const int wc = (wave & 1) * 64;         // wave's quadrant cols
    const int fr = lane & 15;               // MFMA operand row
    const int cg = lane >> 4;               // chunk-group 0..3
    const int srow = tid >> 3;              // staging row within 32-row stripe
    const int schunk = (tid & 7) ^ (srow & 7);  // swizzled global chunk

    // hoisted frag LDS base pointers (kk=0 / kk=32 variants)
    const int fr7 = fr & 7;
    const unsigned short* fA0 = As + (wr + fr) * 64 + ((cg    ) ^ fr7) * 8;
    const unsigned short* fA1 = As + (wr + fr) * 64 + ((cg + 4) ^ fr7) * 8;
    const unsigned short* fB0 = Bs + (wc + fr) * 64 + ((cg    ) ^ fr7) * 8;
    const unsigned short* fB1 = Bs + (wc + fr) * 64 + ((cg + 4) ^ fr7) * 8;

    // staging: uniform base (SGPR-walkable) + loop-invariant lane offset
    const unsigned short* Agu = A  + m0 * (size_t)K;
    const unsigned short* Bgu = Wt + n0 * (size_t)K;
    const int loff = srow * K + schunk * 8;

    f32x4 acc[4][4];
    #pragma unroll
    for (int i = 0; i < 4; i++)
        #pragma unroll
        for (int j = 0; j < 4; j++) acc[i][j] = f32x4{0.f, 0.f, 0.f, 0.f};

    for (int k0 = 0; k0 < K; k0 += 64) {
        const unsigned short* ak = Agu + k0;
        const unsigned short* bk = Bgu + k0;
        #pragma unroll
        for (int s = 0; s < 4; ++s)
            load_lds16(ak + s * 32 * K + loff, &As[(s * 256 + wave * 64) * 8]);
        #pragma unroll
        for (int s = 0; s < 4; ++s)
            load_lds16(bk + s * 32 * K + loff, &Bs[(s * 256 + wave * 64) * 8]);
        __syncthreads();

        bf16x8 af[4], bfr[4];
        #pragma unroll
        for (int i = 0; i < 4; i++) af[i]  = *(const bf16x8*)(fA0 + i * 1024);
        #pragma unroll
        for (int j = 0; j < 4; j++) bfr[j] = *(const bf16x8*)(fB0 + j * 1024);
        #pragma unroll
        for (int i = 0; i < 4; i++)
            #pragma unroll
            for (int j = 0; j < 4; j++)
                acc[i][j] = __builtin_amdgcn_mfma_f32_16x16x32_bf16(
                    af[i], bfr[j], acc[i][j], 0, 0, 0);
        #pragma unroll
        for (int i = 0; i < 4; i++) af[i]  = *(const bf16x8*)(fA1 + i * 1024);
        #pragma unroll
        for (int j = 0; j < 4; j++) bfr[j] = *(const bf16x8*)(fB1 + j * 1024);
        #pragma unroll
        for (int i = 0; i < 4; i++)
            #pragma unroll
            for (int j = 0; j < 4; j++)
                acc[i][j] = __builtin_amdgcn_mfma_f32_16x16x32_bf16(
                    af[i], bfr[j], acc[i][j], 0, 0, 0);
        __syncthreads();
    }

    // C/D layout (verified m89/m91): col = lane&15, row = (lane>>4)*4 + reg
    const int rbase = wr + (lane >> 4) * 4;
    const int cbase = wc + (lane & 15);
    #pragma unroll
    for (int j = 0; j < 4; j++) {
        const int col = (int)n0 + cbase + j * 16;
        const float bv = bias[col];
        #pragma unroll
        for (int i = 0; i < 4; i++) {
            float* cp = C + (m0 + rbase + i * 16) * N + col;
            #pragma unroll
            for (int r = 0; r < 4; r++) cp[(size_t)r * N] = acc[i][j][r] + bv;
        }
    }
}

extern "C" void kernel_launch(void* const* d_in, const int* in_sizes, int n_in,
                              void* d_out, int out_size, void* d_ws, size_t ws_size,
                              hipStream_t stream)
{
    const float* x       = (const float*)d_in[0];
    const float* coeff1  = (const float*)d_in[1];
    const float* base_w1 = (const float*)d_in[2];
    const float* bias1   = (const float*)d_in[3];
    const float* gamma   = (const float*)d_in[4];
    const float* beta    = (const float*)d_in[5];
    const float* coeff2  = (const float*)d_in[6];
    const float* base_w2 = (const float*)d_in[7];
    const float* bias2   = (const float*)d_in[8];
    float* out = (float*)d_out;

    const int B = 16384, D0 = 1024, D1 = 1024, D2 = 512;
    const int K1 = D0 * 6, K2 = D1 * 6;   // 6144 each

    // workspace layout
    char* base = (char*)d_ws;
    size_t off = 0;
    unsigned short* W1 = (unsigned short*)(base + off); off += (size_t)D1 * K1 * 2;
    unsigned short* W2 = (unsigned short*)(base + off); off += (size_t)D2 * K2 * 2;
    float* b1p = (float*)(base + off); off += (size_t)D1 * 4;
    float* b2p = (float*)(base + off); off += (size_t)D2 * 4;
    off = (off + 255) & ~(size_t)255;

    // chunk rows so Xaug (K1 bf16) + h (D1 f32) fit in remaining ws; keep %128
    size_t per_row = (size_t)K1 * 2 + (size_t)D1 * 4;   // 16384 B
    long long avail = (long long)ws_size - (long long)off;
    long long mcl = avail > 0 ? avail / (long long)per_row : 0;
    int Mc = (int)((mcl / 128) * 128);
    if (Mc < 128) Mc = 128;
    if (Mc > B) Mc = B;

    unsigned short* Xa = (unsigned short*)(base + off);
    float* h = (float*)(base + off + (size_t)Mc * K1 * 2);

    prep_w_kernel<<<(D1 * D0 + 255) / 256, 256, 0, stream>>>(coeff1, base_w1, W1, D1 * D0);
    prep_w_kernel<<<(D2 * D1 + 255) / 256, 256, 0, stream>>>(coeff2, base_w2, W2, D2 * D1);
    prep_bias_kernel<<<D1, 256, 0, stream>>>(coeff1, bias1, b1p, D0);
    prep_bias_kernel<<<D2, 256, 0, stream>>>(coeff2, bias2, b2p, D1);

    for (int m0 = 0; m0 < B; m0 += Mc) {
        int rows = (B - m0 < Mc) ? (B - m0) : Mc;
        expand1_kernel<<<rows, 256, 0, stream>>>(x + (size_t)m0 * D0, Xa);
        gemm_kernel<<<(rows / 128) * (D1 / 128), 256, 0, stream>>>(
            Xa, W1, b1p, h, D1, K1);
        ln_silu_expand_kernel<<<rows, 256, 0, stream>>>(h, gamma, beta, Xa);
        gemm_kernel<<<(rows / 128) * (D2 / 128), 256, 0, stream>>>(
            Xa, W2, b2p, out + (size_t)m0 * D2, D2, K2);
    }
}

// Round 5
// 629.550 us; speedup vs baseline: 1.8090x; 1.5073x over previous
//
#include <hip/hip_runtime.h>

// ChebyshevKAN on MI355X (gfx950).
// Reformulation: einsum(bid,oid->bo) + x@base_w.T  ==  Xaug @ W^T with
//   Xaug[b, i*6+d] = T_{d+1}(tanh(x_i))  (d=0..4),  Xaug[b, i*6+5] = x_i
//   W[o,    i*6+d] = coeff[o,i,d+1]      (d=0..4),  W[o,    i*6+5] = base_w[o,i]
// T0==1 slice folds into bias:  bias'[o] = bias[o] + sum_i coeff[o,i,0].
// GEMMs run bf16 MFMA (16x16x32), fp32 accumulate; nonlinearity in fp32.
//
// R5: (1) __launch_bounds__(256,4) -> 4 blocks/CU (64 AGPR + <=64 VGPR),
// grid 1024 all-resident, kills the 256-block tail that held occupancy at
// 20.6%; (2) gemm2 BM=64 -> grid 1024 (was 512 = 2/CU forever); (3) h in
// bf16 (halves the h round-trip). XCD swizzle kept (verified harmless);
// XOR LDS swizzle kept (SQ_LDS_BANK_CONFLICT==0 since R2).

typedef __bf16 bf16x8 __attribute__((ext_vector_type(8)));
typedef float f32x4 __attribute__((ext_vector_type(4)));
typedef unsigned short u16x8 __attribute__((ext_vector_type(8)));

__device__ __forceinline__ unsigned short f2bf(float f) {
    unsigned int u = __float_as_uint(f);
    unsigned int r = (u + 0x7FFFu + ((u >> 16) & 1u)) >> 16;
    return (unsigned short)r;
}
__device__ __forceinline__ float bf2f(unsigned short b) {
    return __uint_as_float(((unsigned int)b) << 16);
}

// tanh via hardware exp/rcp: err ~1e-6, way below bf16 quantization.
__device__ __forceinline__ float fast_tanh(float x) {
    float a = fminf(fmaxf(x, -15.f), 15.f);
    float e = __expf(2.f * a);
    return 1.f - 2.f * __builtin_amdgcn_rcpf(e + 1.f);
}
__device__ __forceinline__ float fast_silu(float y) {
    float a = fminf(fmaxf(y, -30.f), 30.f);
    return y * __builtin_amdgcn_rcpf(1.f + __expf(-a));
}

__device__ __forceinline__ void cheb_pack(float s, unsigned short* o6) {
    float u  = fast_tanh(s);
    float T1 = u;
    float T2 = 2.f * u * u - 1.f;
    float T3 = 2.f * u * T2 - T1;
    float T4 = 2.f * u * T3 - T2;
    float T5 = 2.f * u * T4 - T3;
    o6[0] = f2bf(T1); o6[1] = f2bf(T2); o6[2] = f2bf(T3);
    o6[3] = f2bf(T4); o6[4] = f2bf(T5); o6[5] = f2bf(s);
}

__device__ __forceinline__ void load_lds16(const void* g, void* l) {
    __builtin_amdgcn_global_load_lds(
        (const __attribute__((address_space(1))) void*)g,
        (__attribute__((address_space(3))) void*)l, 16, 0, 0);
}

// ---------------- prep: weights [O,I,6]+[O,I] -> W[N=O, K=I*6] bf16 ----------
__global__ __launch_bounds__(256) void prep_w_kernel(
    const float* __restrict__ coeff, const float* __restrict__ base_w,
    unsigned short* __restrict__ W, int OI)
{
    int idx = blockIdx.x * 256 + threadIdx.x;
    if (idx >= OI) return;
    const float* c = coeff + (size_t)idx * 6;
    unsigned short w0 = f2bf(c[1]), w1 = f2bf(c[2]), w2 = f2bf(c[3]),
                   w3 = f2bf(c[4]), w4 = f2bf(c[5]), w5 = f2bf(base_w[idx]);
    unsigned int* d = (unsigned int*)(W + (size_t)idx * 6);
    d[0] = w0 | ((unsigned int)w1 << 16);
    d[1] = w2 | ((unsigned int)w3 << 16);
    d[2] = w4 | ((unsigned int)w5 << 16);
}

// bias'[o] = bias[o] + sum_i coeff[o,i,0]   (fp32, block per o)
__global__ __launch_bounds__(256) void prep_bias_kernel(
    const float* __restrict__ coeff, const float* __restrict__ bias,
    float* __restrict__ bp, int I)
{
    int o = blockIdx.x, tid = threadIdx.x;
    float s = 0.f;
    for (int i = tid; i < I; i += 256) s += coeff[((size_t)o * I + i) * 6];
    #pragma unroll
    for (int off = 32; off > 0; off >>= 1) s += __shfl_down(s, off);
    __shared__ float red[4];
    int lane = tid & 63, wv = tid >> 6;
    if (lane == 0) red[wv] = s;
    __syncthreads();
    if (tid == 0) bp[o] = bias[o] + red[0] + red[1] + red[2] + red[3];
}

// ---------------- expand1: x[b,1024] -> Xaug[b,6144] bf16  (block per row) ---
__global__ __launch_bounds__(256) void expand1_kernel(
    const float* __restrict__ x, unsigned short* __restrict__ Xa)
{
    int b = blockIdx.x, tid = threadIdx.x;
    f32x4 xv = *(const f32x4*)(x + (size_t)b * 1024 + tid * 4);
    alignas(16) unsigned short ov[24];
    #pragma unroll
    for (int e = 0; e < 4; e++) cheb_pack(fast_tanh(xv[e]), ov + e * 6);
    u16x8* dst = (u16x8*)(Xa + (size_t)b * 6144 + tid * 24);
    const u16x8* src = (const u16x8*)ov;
    dst[0] = src[0]; dst[1] = src[1]; dst[2] = src[2];
}

// ------------- LN + SiLU + expand2 fused (block per row of 1024, h in bf16) --
__global__ __launch_bounds__(256) void ln_silu_expand_kernel(
    const unsigned short* __restrict__ H, const float* __restrict__ gamma,
    const float* __restrict__ beta, unsigned short* __restrict__ Xa)
{
    int b = blockIdx.x, tid = threadIdx.x;
    ushort4 hb = *(const ushort4*)(H + (size_t)b * 1024 + tid * 4);
    float hv[4] = { bf2f(hb.x), bf2f(hb.y), bf2f(hb.z), bf2f(hb.w) };
    float s1 = hv[0] + hv[1] + hv[2] + hv[3];
    float s2 = hv[0]*hv[0] + hv[1]*hv[1] + hv[2]*hv[2] + hv[3]*hv[3];
    #pragma unroll
    for (int off = 32; off > 0; off >>= 1) {
        s1 += __shfl_down(s1, off);
        s2 += __shfl_down(s2, off);
    }
    __shared__ float red[8];
    __shared__ float stats[2];
    int lane = tid & 63, wv = tid >> 6;
    if (lane == 0) { red[wv] = s1; red[4 + wv] = s2; }
    __syncthreads();
    if (tid == 0) {
        float t1 = red[0] + red[1] + red[2] + red[3];
        float t2 = red[4] + red[5] + red[6] + red[7];
        float mu = t1 * (1.f / 1024.f);
        float var = t2 * (1.f / 1024.f) - mu * mu;
        stats[0] = mu;
        stats[1] = rsqrtf(var + 1e-5f);
    }
    __syncthreads();
    float mu = stats[0], rs = stats[1];
    f32x4 g  = *(const f32x4*)(gamma + tid * 4);
    f32x4 bt = *(const f32x4*)(beta  + tid * 4);
    alignas(16) unsigned short ov[24];
    #pragma unroll
    for (int e = 0; e < 4; e++) {
        float y = (hv[e] - mu) * rs * g[e] + bt[e];
        cheb_pack(fast_silu(y), ov + e * 6);
    }
    u16x8* dst = (u16x8*)(Xa + (size_t)b * 6144 + tid * 24);
    const u16x8* src = (const u16x8*)ov;
    dst[0] = src[0]; dst[1] = src[1]; dst[2] = src[2];
}

// ---------------- bf16 GEMM: C[M,N] = A[M,K] * W[N,K]^T + bias ---------------
// BM x 128 tile, BK=64, global_load_lds width-16 staging with XOR chunk
// swizzle (SQ_LDS_BANK_CONFLICT==0); 4 waves, each a (BM/2) x 64 quadrant of
// (BM/32) x 4 16x16x32 MFMAs. Frag LDS pointers hoisted. launch_bounds
// (256,4): AGPR(16*MI) + VGPR <= 128/wave -> 4 blocks/CU, grid 1024
// all-resident, no tail.
template<int BM, bool OUT_BF16>
__global__ __launch_bounds__(256, 4) void gemm_kernel(
    const unsigned short* __restrict__ A,   // [M,K] bf16 bits
    const unsigned short* __restrict__ Wt,  // [N,K] bf16 bits
    const float* __restrict__ bias,         // [N]
    void* __restrict__ Cout,                // [M,N] f32 or bf16
    int N, int K)
{
    constexpr int MI = BM / 32;
    __shared__ __align__(16) unsigned short As[BM * 64];
    __shared__ __align__(16) unsigned short Bs[128 * 64];
    const int tid  = threadIdx.x;
    const int lane = tid & 63;
    const int wave = tid >> 6;
    const int ntn  = N >> 7;

    // XCD-affinity swizzle (verified harmless; bijective)
    int bkid = blockIdx.x;
    const int nm = gridDim.x / ntn;
    int mt, nt;
    if ((nm & 7) == 0) {
        const int mg = nm >> 3;
        const int s  = bkid >> 3;
        const int q  = s / ntn;
        mt = (bkid & 7) * mg + q;
        nt = s - q * ntn;
    } else {
        mt = bkid / ntn; nt = bkid % ntn;
    }
    const size_t m0 = (size_t)mt * BM;
    const size_t n0 = (size_t)nt << 7;

    const int wr = (wave >> 1) * (BM / 2);  // wave's quadrant rows
    const int wc = (wave & 1) * 64;         // wave's quadrant cols
    const int fr = lane & 15;               // MFMA operand row
    const int cg = lane >> 4;               // chunk-group 0..3
    const int srow = tid >> 3;              // staging row within 32-row stripe
    const int schunk = (tid & 7) ^ (srow & 7);  // swizzled global chunk

    // hoisted frag LDS base pointers (kk=0 / kk=32 variants)
    const int fr7 = fr & 7;
    const unsigned short* fA0 = As + (wr + fr) * 64 + ((cg    ) ^ fr7) * 8;
    const unsigned short* fA1 = As + (wr + fr) * 64 + ((cg + 4) ^ fr7) * 8;
    const unsigned short* fB0 = Bs + (wc + fr) * 64 + ((cg    ) ^ fr7) * 8;
    const unsigned short* fB1 = Bs + (wc + fr) * 64 + ((cg + 4) ^ fr7) * 8;

    const unsigned short* Agu = A  + m0 * (size_t)K;
    const unsigned short* Bgu = Wt + n0 * (size_t)K;
    const int loff = srow * K + schunk * 8;

    f32x4 acc[MI][4];
    #pragma unroll
    for (int i = 0; i < MI; i++)
        #pragma unroll
        for (int j = 0; j < 4; j++) acc[i][j] = f32x4{0.f, 0.f, 0.f, 0.f};

    for (int k0 = 0; k0 < K; k0 += 64) {
        const unsigned short* ak = Agu + k0;
        const unsigned short* bk = Bgu + k0;
        #pragma unroll
        for (int s = 0; s < BM / 32; ++s)
            load_lds16(ak + s * 32 * K + loff, &As[(s * 256 + wave * 64) * 8]);
        #pragma unroll
        for (int s = 0; s < 4; ++s)
            load_lds16(bk + s * 32 * K + loff, &Bs[(s * 256 + wave * 64) * 8]);
        __syncthreads();

        bf16x8 af[MI], bfr[4];
        #pragma unroll
        for (int i = 0; i < MI; i++) af[i]  = *(const bf16x8*)(fA0 + i * 1024);
        #pragma unroll
        for (int j = 0; j < 4; j++)  bfr[j] = *(const bf16x8*)(fB0 + j * 1024);
        #pragma unroll
        for (int i = 0; i < MI; i++)
            #pragma unroll
            for (int j = 0; j < 4; j++)
                acc[i][j] = __builtin_amdgcn_mfma_f32_16x16x32_bf16(
                    af[i], bfr[j], acc[i][j], 0, 0, 0);
        #pragma unroll
        for (int i = 0; i < MI; i++) af[i]  = *(const bf16x8*)(fA1 + i * 1024);
        #pragma unroll
        for (int j = 0; j < 4; j++)  bfr[j] = *(const bf16x8*)(fB1 + j * 1024);
        #pragma unroll
        for (int i = 0; i < MI; i++)
            #pragma unroll
            for (int j = 0; j < 4; j++)
                acc[i][j] = __builtin_amdgcn_mfma_f32_16x16x32_bf16(
                    af[i], bfr[j], acc[i][j], 0, 0, 0);
        __syncthreads();
    }

    // C/D layout (verified m89/m91): col = lane&15, row = (lane>>4)*4 + reg
    const int rbase = wr + (lane >> 4) * 4;
    const int cbase = wc + (lane & 15);
    #pragma unroll
    for (int j = 0; j < 4; j++) {
        const int col = (int)n0 + cbase + j * 16;
        const float bv = bias[col];
        #pragma unroll
        for (int i = 0; i < MI; i++) {
            #pragma unroll
            for (int r = 0; r < 4; r++) {
                const size_t idx = (m0 + rbase + i * 16 + r) * N + col;
                if (OUT_BF16)
                    ((unsigned short*)Cout)[idx] = f2bf(acc[i][j][r] + bv);
                else
                    ((float*)Cout)[idx] = acc[i][j][r] + bv;
            }
        }
    }
}

extern "C" void kernel_launch(void* const* d_in, const int* in_sizes, int n_in,
                              void* d_out, int out_size, void* d_ws, size_t ws_size,
                              hipStream_t stream)
{
    const float* x       = (const float*)d_in[0];
    const float* coeff1  = (const float*)d_in[1];
    const float* base_w1 = (const float*)d_in[2];
    const float* bias1   = (const float*)d_in[3];
    const float* gamma   = (const float*)d_in[4];
    const float* beta    = (const float*)d_in[5];
    const float* coeff2  = (const float*)d_in[6];
    const float* base_w2 = (const float*)d_in[7];
    const float* bias2   = (const float*)d_in[8];
    float* out = (float*)d_out;

    const int B = 16384, D0 = 1024, D1 = 1024, D2 = 512;
    const int K1 = D0 * 6, K2 = D1 * 6;   // 6144 each

    // workspace layout
    char* base = (char*)d_ws;
    size_t off = 0;
    unsigned short* W1 = (unsigned short*)(base + off); off += (size_t)D1 * K1 * 2;
    unsigned short* W2 = (unsigned short*)(base + off); off += (size_t)D2 * K2 * 2;
    float* b1p = (float*)(base + off); off += (size_t)D1 * 4;
    float* b2p = (float*)(base + off); off += (size_t)D2 * 4;
    off = (off + 255) & ~(size_t)255;

    // chunk rows: Xaug (K1 bf16) + h (D1 bf16) per row; keep %128
    size_t per_row = (size_t)K1 * 2 + (size_t)D1 * 2;   // 14336 B
    long long avail = (long long)ws_size - (long long)off;
    long long mcl = avail > 0 ? avail / (long long)per_row : 0;
    int Mc = (int)((mcl / 128) * 128);
    if (Mc < 128) Mc = 128;
    if (Mc > B) Mc = B;

    unsigned short* Xa = (unsigned short*)(base + off);
    unsigned short* h = (unsigned short*)(base + off + (size_t)Mc * K1 * 2);

    prep_w_kernel<<<(D1 * D0 + 255) / 256, 256, 0, stream>>>(coeff1, base_w1, W1, D1 * D0);
    prep_w_kernel<<<(D2 * D1 + 255) / 256, 256, 0, stream>>>(coeff2, base_w2, W2, D2 * D1);
    prep_bias_kernel<<<D1, 256, 0, stream>>>(coeff1, bias1, b1p, D0);
    prep_bias_kernel<<<D2, 256, 0, stream>>>(coeff2, bias2, b2p, D1);

    for (int m0 = 0; m0 < B; m0 += Mc) {
        int rows = (B - m0 < Mc) ? (B - m0) : Mc;
        expand1_kernel<<<rows, 256, 0, stream>>>(x + (size_t)m0 * D0, Xa);
        gemm_kernel<128, true><<<(rows / 128) * (D1 / 128), 256, 0, stream>>>(
            Xa, W1, b1p, h, D1, K1);
        ln_silu_expand_kernel<<<rows, 256, 0, stream>>>(h, gamma, beta, Xa);
        gemm_kernel<64, false><<<(rows / 64) * (D2 / 128), 256, 0, stream>>>(
            Xa, W2, b2p, out + (size_t)m0 * D2, D2, K2);
    }
}